// Round 1
// baseline (441.602 us; speedup 1.0000x reference)
//
#include <hip/hip_runtime.h>

// W8A8Linear: out[m,o] = x_scale * w_scale[o] * dot_i8(x_q[m,:], w_q[o,:]) + bias[o]
// M = B*S = 8192, K = DIN = 4096, N = DOUT = 4096.

#define DIN   4096
#define DOUT  4096
#define MTOT  8192

#define BM 128
#define BN 128
#define BK 64   // bytes of K per tile (i8)

typedef int v4i __attribute__((ext_vector_type(4)));

__device__ inline void gload_lds16(const void* g, void* l) {
    // 16-byte-per-lane async global->LDS. LDS dest = wave-uniform base + lane*16.
    __builtin_amdgcn_global_load_lds(
        (const __attribute__((address_space(1))) int*)g,
        (__attribute__((address_space(3))) int*)l,
        16, 0, 0);
}

// Quantize fp32 -> int8: q = clamp(rint(v * inv_scale), -128, 127). RTE matches jnp.round.
__global__ void quant_kernel(const float* __restrict__ src, char* __restrict__ dst,
                             int n4, const float* __restrict__ scale_ptr) {
    float inv_s = 1.0f;
    if (scale_ptr) inv_s = 1.0f / scale_ptr[0];
    int stride = gridDim.x * blockDim.x;
    for (int i = blockIdx.x * blockDim.x + threadIdx.x; i < n4; i += stride) {
        float4 v = reinterpret_cast<const float4*>(src)[i];
        int q0 = (int)rintf(v.x * inv_s);
        int q1 = (int)rintf(v.y * inv_s);
        int q2 = (int)rintf(v.z * inv_s);
        int q3 = (int)rintf(v.w * inv_s);
        q0 = max(-128, min(127, q0));
        q1 = max(-128, min(127, q1));
        q2 = max(-128, min(127, q2));
        q3 = max(-128, min(127, q3));
        int packed = (q0 & 255) | ((q1 & 255) << 8) | ((q2 & 255) << 16) | ((q3 & 255) << 24);
        reinterpret_cast<int*>(dst)[i] = packed;
    }
}

// i8 GEMM, m97 structure: 128x128 tile, BK=64, 4 waves (2x2), 2-barrier K-loop,
// global_load_lds width-16 staging, mfma_i32_16x16x64_i8.
__global__ __launch_bounds__(256)
void gemm_i8_kernel(const char* __restrict__ Aq,   // [MTOT][DIN] int8
                    const char* __restrict__ Bq,   // [DOUT][DIN] int8
                    const float* __restrict__ w_scale,
                    const float* __restrict__ bias,
                    const float* __restrict__ x_scale,
                    float* __restrict__ out) {     // [MTOT][DOUT] f32
    __shared__ char lds_a[BM * BK];   // 8 KiB
    __shared__ char lds_b[BN * BK];   // 8 KiB

    const int tid  = threadIdx.x;
    const int lane = tid & 63;
    const int wave = tid >> 6;
    const int bid  = blockIdx.x;
    const int bm   = bid >> 5;        // 64 row-blocks
    const int bn   = bid & 31;        // 32 col-blocks

    const int wr = wave >> 1;         // wave's 64x64 sub-tile
    const int wc = wave & 1;

    v4i acc[4][4] = {};

    // staging: chunk c = it*256 + tid; row = c>>2 (16B x 4 lanes per 64B row), inner = (c&3)*16
    const int srow  = tid >> 2;
    const int sinner = (tid & 3) * 16;
    const char* gA = Aq + (size_t)(bm * BM + srow) * DIN + sinner;
    const char* gB = Bq + (size_t)(bn * BN + srow) * DIN + sinner;

    const int arow_off = (wr * 64 + (lane & 15)) * BK + (lane >> 4) * 16;
    const int brow_off = (wc * 64 + (lane & 15)) * BK + (lane >> 4) * 16;

    for (int kt = 0; kt < DIN / BK; ++kt) {
        const int koff = kt * BK;
        // stage A (2 insts) and B (2 insts); each wave writes a contiguous 1 KiB chunk
        gload_lds16(gA + koff,                lds_a + wave * 1024);
        gload_lds16(gA + koff + 64 * DIN,     lds_a + 4096 + wave * 1024);
        gload_lds16(gB + koff,                lds_b + wave * 1024);
        gload_lds16(gB + koff + 64 * DIN,     lds_b + 4096 + wave * 1024);
        __syncthreads();   // drains vmcnt

        v4i afrag[4], bfrag[4];
#pragma unroll
        for (int mi = 0; mi < 4; ++mi)
            afrag[mi] = *reinterpret_cast<const v4i*>(&lds_a[arow_off + mi * 16 * BK]);
#pragma unroll
        for (int ni = 0; ni < 4; ++ni)
            bfrag[ni] = *reinterpret_cast<const v4i*>(&lds_b[brow_off + ni * 16 * BK]);

#pragma unroll
        for (int mi = 0; mi < 4; ++mi)
#pragma unroll
            for (int ni = 0; ni < 4; ++ni)
                acc[mi][ni] = __builtin_amdgcn_mfma_i32_16x16x64_i8(
                    afrag[mi], bfrag[ni], acc[mi][ni], 0, 0, 0);

        __syncthreads();
    }

    // epilogue: C/D layout (16x16): col = lane&15, row = (lane>>4)*4 + j
    const float xs = x_scale[0];
    const int row0 = bm * BM + wr * 64 + (lane >> 4) * 4;
    const int col0 = bn * BN + wc * 64 + (lane & 15);
#pragma unroll
    for (int ni = 0; ni < 4; ++ni) {
        const int col = col0 + ni * 16;
        const float s = xs * w_scale[col];
        const float bb = bias[col];
#pragma unroll
        for (int mi = 0; mi < 4; ++mi) {
            const int row = row0 + mi * 16;
#pragma unroll
            for (int j = 0; j < 4; ++j)
                out[(size_t)(row + j) * DOUT + col] = (float)acc[mi][ni][j] * s + bb;
        }
    }
}

extern "C" void kernel_launch(void* const* d_in, const int* in_sizes, int n_in,
                              void* d_out, int out_size, void* d_ws, size_t ws_size,
                              hipStream_t stream) {
    const float* x        = (const float*)d_in[0];  // [4,2048,4096]
    const float* w_f32    = (const float*)d_in[1];  // [4096,4096] (int values in f32)
    const float* w_scale  = (const float*)d_in[2];  // [4096]
    const float* bias     = (const float*)d_in[3];  // [4096]
    const float* x_scale  = (const float*)d_in[4];  // [1]
    float* out            = (float*)d_out;          // [4,2048,4096]

    char* Aq = (char*)d_ws;                              // 32 MiB
    char* Bq = (char*)d_ws + (size_t)MTOT * DIN;         // 16 MiB

    // quantize x (with x_scale) and convert weight (already integral)
    quant_kernel<<<4096, 256, 0, stream>>>(x, Aq, (MTOT * DIN) / 4, x_scale);
    quant_kernel<<<2048, 256, 0, stream>>>(w_f32, Bq, (DOUT * DIN) / 4, nullptr);

    // GEMM: grid = (M/128) * (N/128) = 64*32 = 2048
    gemm_i8_kernel<<<2048, 256, 0, stream>>>(Aq, Bq, w_scale, bias, x_scale, out);
}